// Round 5
// baseline (1649.032 us; speedup 1.0000x reference)
//
#include <hip/hip_runtime.h>
#include <stdint.h>

// Problem dims (fixed): T=256, B=128, I=512, H=1024, O=1
typedef __attribute__((ext_vector_type(8))) short short8;
typedef __attribute__((ext_vector_type(4))) float f32x4;
typedef __attribute__((ext_vector_type(4))) unsigned int u32x4;

__device__ __forceinline__ unsigned short f2bf(float f) {
  unsigned u = __float_as_uint(f);
  u += 0x7FFFu + ((u >> 16) & 1u);   // RNE
  return (unsigned short)(u >> 16);
}
__device__ __forceinline__ float bf2f(unsigned short s) {
  return __uint_as_float(((unsigned)s) << 16);
}
__device__ __forceinline__ float ftanh(float x) {
  float e = __expf(2.0f * x);
  return 1.0f - 2.0f / (e + 1.0f);
}
__device__ __forceinline__ bool tag4(u32x4 v, unsigned e) {
  return (v.x >> 16) == e && (v.y >> 16) == e && (v.z >> 16) == e && (v.w >> 16) == e;
}

// ---------------- fp32 -> bf16 convert (vectorized, 8 elem/thread) ----------
__global__ __launch_bounds__(256) void cvt_kernel(const float* __restrict__ in,
                                                  unsigned short* __restrict__ out,
                                                  int n8) {
  int i = blockIdx.x * 256 + threadIdx.x;
  if (i >= n8) return;
  const float4* p = (const float4*)in + (size_t)i * 2;
  float4 a = p[0], b = p[1];
  uint4 o;
  o.x = (unsigned)f2bf(a.x) | ((unsigned)f2bf(a.y) << 16);
  o.y = (unsigned)f2bf(a.z) | ((unsigned)f2bf(a.w) << 16);
  o.z = (unsigned)f2bf(b.x) | ((unsigned)f2bf(b.y) << 16);
  o.w = (unsigned)f2bf(b.z) | ((unsigned)f2bf(b.w) << 16);
  ((uint4*)out)[i] = o;
}

// ---------------- xp GEMM: xp[m][n] = sum_k x[m][k]*W_ih[n][k] + b_ih[n]+b_hh[n]
__global__ __launch_bounds__(256) void gemm_xp(const unsigned short* __restrict__ A,
                                               const unsigned short* __restrict__ Bw,
                                               const float* __restrict__ b_ih,
                                               const float* __restrict__ b_hh,
                                               unsigned short* __restrict__ xp) {
  __shared__ unsigned short Al[8192];
  __shared__ unsigned short Bl[8192];
  int tid = threadIdx.x, lane = tid & 63, w = tid >> 6;
  int wm = w & 1, wn = w >> 1;
  int bx = blockIdx.x;
  int m0 = (bx >> 3) * 128, n0 = (bx & 7) * 128;

  f32x4 acc[4][4];
#pragma unroll
  for (int i = 0; i < 4; ++i)
#pragma unroll
    for (int jq = 0; jq < 4; ++jq) acc[i][jq] = (f32x4){0.f, 0.f, 0.f, 0.f};

  for (int kb = 0; kb < 512; kb += 64) {
#pragma unroll
    for (int i = 0; i < 4; ++i) {
      int S = (w * 4 + i) * 64 + lane;
      int row = S >> 3, pg = S & 7;
      int gk = ((pg ^ (row & 7)) << 3);
      const unsigned short* ga = A + (size_t)(m0 + row) * 512 + kb + gk;
      const unsigned short* gb = Bw + (size_t)(n0 + row) * 512 + kb + gk;
      __builtin_amdgcn_global_load_lds(
          (const __attribute__((address_space(1))) unsigned int*)ga,
          (__attribute__((address_space(3))) unsigned int*)&Al[(size_t)((w * 4 + i) * 64) * 8],
          16, 0, 0);
      __builtin_amdgcn_global_load_lds(
          (const __attribute__((address_space(1))) unsigned int*)gb,
          (__attribute__((address_space(3))) unsigned int*)&Bl[(size_t)((w * 4 + i) * 64) * 8],
          16, 0, 0);
    }
    asm volatile("s_waitcnt vmcnt(0)" ::: "memory");
    __syncthreads();

#pragma unroll
    for (int c = 0; c < 2; ++c) {
      short8 av[4], bv[4];
      int gg = c * 4 + (lane >> 4);
#pragma unroll
      for (int mt = 0; mt < 4; ++mt) {
        int rowa = wm * 64 + mt * 16 + (lane & 15);
        av[mt] = *(const short8*)&Al[(rowa * 8 + (gg ^ (rowa & 7))) * 8];
        int rowb = wn * 64 + mt * 16 + (lane & 15);
        bv[mt] = *(const short8*)&Bl[(rowb * 8 + (gg ^ (rowb & 7))) * 8];
      }
#pragma unroll
      for (int mt = 0; mt < 4; ++mt)
#pragma unroll
        for (int nt = 0; nt < 4; ++nt)
          acc[mt][nt] = __builtin_amdgcn_mfma_f32_16x16x32_bf16(av[mt], bv[nt], acc[mt][nt], 0, 0, 0);
    }
    __syncthreads();
  }

  int cl = lane & 15, qd = lane >> 4;
#pragma unroll
  for (int nt = 0; nt < 4; ++nt) {
    int col = n0 + wn * 64 + nt * 16 + cl;
    float bias = b_ih[col] + b_hh[col];
#pragma unroll
    for (int mt = 0; mt < 4; ++mt) {
#pragma unroll
      for (int r = 0; r < 4; ++r) {
        int m = m0 + wm * 64 + mt * 16 + qd * 4 + r;
        xp[(size_t)m * 1024 + col] = f2bf(acc[mt][nt][r] + bias);
      }
    }
  }
}

// ---------------- the scan -------------------------------------------------
// 64 WGs x 512 threads (8 waves): group g = blk>>3 (16 batches), producer
// p = blk&7 owns cols [p*128,p*128+128); wave w owns the 16x16 tile at
// p*128+w*16. W_hh B-frags in AGPR/VGPR (128/wave, r4-proven).
// ONE MALL round trip/step: h published as self-validating (s<<16)|bf16
// dwords, sc0 sc1 fire-and-forget (no vmcnt ack, no tag store). Consumers
// two-phase poll their 128-B run (sentinels first: 32 B/round), strip into
// XOR-swizzled LDS Abuf. Two barriers/step. 2-slot buffer race-free by
// backpressure (publish of h[s] implies full consumption of h[s-1]).
// Head partials -> private pscratch slots (plain stores, zero contention);
// summed by a trailing reduce kernel. No atomics anywhere.
__global__ __launch_bounds__(512, 2) void scan_kernel(
    const float* __restrict__ Whh, const unsigned short* __restrict__ xp,
    const float* __restrict__ Wfc, unsigned* __restrict__ hbuf,
    float* __restrict__ pscratch) {
  __shared__ __align__(16) unsigned short Abuf[2048 * 8];  // 32 KB
  const int tid = threadIdx.x;
  const int lane = tid & 63, w = tid >> 6;
  const int g = blockIdx.x >> 3, p = blockIdx.x & 7;
  const int r = lane & 15, q = lane >> 4;
  const int b0 = g * 16;
  const int gcol = p * 128 + w * 16 + r;   // this lane's output column
  const float wfcv = Wfc[gcol];
  const int bb = tid >> 5, cb = tid & 31;  // poll assignment: batch bb, cols cb*32..+31

  // ---- W_hh -> B-frags: lane (r,q) holds W[gcol][c*32+q*8 ..+7]
  short8 Bfrag[32];
  {
    const float* wsrc = Whh + (size_t)gcol * 1024 + q * 8;
#pragma unroll
    for (int c = 0; c < 32; ++c) {
      float4 v0 = *(const float4*)(wsrc + c * 32);
      float4 v1 = *(const float4*)(wsrc + c * 32 + 4);
      short8 sv;
      sv[0] = (short)f2bf(v0.x); sv[1] = (short)f2bf(v0.y);
      sv[2] = (short)f2bf(v0.z); sv[3] = (short)f2bf(v0.w);
      sv[4] = (short)f2bf(v1.x); sv[5] = (short)f2bf(v1.y);
      sv[6] = (short)f2bf(v1.z); sv[7] = (short)f2bf(v1.w);
      Bfrag[c] = sv;
    }
  }

  // ---- step 0: full h0 = tanh(xp[0]) locally into Abuf (swizzled) + head.
  {
    float pp = 0.f;
#pragma unroll
    for (int i = 0; i < 4; ++i) {
      int c = w + i * 8;                       // lane part: batch r, k-group q
      const unsigned short* src = xp + (size_t)(b0 + r) * 1024 + c * 32 + q * 8;
      u32x4 xv = *(const u32x4*)src;
      const unsigned short* xs = (const unsigned short*)&xv;
      short8 sv;
#pragma unroll
      for (int jj = 0; jj < 8; ++jj) {
        float h = ftanh(bf2f(xs[jj]));
        sv[jj] = (short)f2bf(h);
        pp += h * Wfc[c * 32 + q * 8 + jj];
      }
      *(short8*)&Abuf[(size_t)(c * 64 + (lane ^ (c & 7))) * 8] = sv;
    }
    pp += __shfl_xor(pp, 16, 64);
    pp += __shfl_xor(pp, 32, 64);            // now per-batch (lane&15) sum over q
    if (lane < 16)                            // o = 0*128 + b0 + lane
      pscratch[(size_t)(b0 + lane) * 64 + p * 8 + w] = (p == 0) ? pp : 0.f;
  }
  __syncthreads();

  // xp prefetch for s=1
  float xpv[4];
#pragma unroll
  for (int rr = 0; rr < 4; ++rr)
    xpv[rr] = bf2f(xp[((size_t)1 * 128 + b0 + q * 4 + rr) * 1024 + gcol]);

  for (int s = 1; s < 256; ++s) {
    if (s >= 2) {
      // ---- poll tagged h[s-1]: thread owns a contiguous 128-B run.
      const unsigned exp_tag = (unsigned)(s - 1);
      const unsigned* pb = hbuf + (size_t)((((s - 1) & 1) * 8 + g) * 16 + bb) * 1024 + cb * 32;
      u32x4 pc[8];
      int guard = 0;
      // Phase A: sentinels (pieces 0 and 4) — 32 B per round while waiting.
      unsigned okA = 0;
      while (okA != 3u) {
        if (!(okA & 1u))
          asm volatile("global_load_dwordx4 %0, %1, off sc0 sc1" : "=v"(pc[0])
                       : "v"((unsigned long long)(uintptr_t)pb) : "memory");
        if (!(okA & 2u))
          asm volatile("global_load_dwordx4 %0, %1, off sc0 sc1" : "=v"(pc[4])
                       : "v"((unsigned long long)(uintptr_t)(pb + 16)) : "memory");
        asm volatile("s_waitcnt vmcnt(0)" ::: "memory");
        if (tag4(pc[0], exp_tag)) okA |= 1u;
        if (tag4(pc[4], exp_tag)) okA |= 2u;
        if (++guard > (1 << 18)) break;  // fail-safe: terminate (fails check)
      }
      // Phase B: remaining 6 pieces (usually ready on first try).
      unsigned ok = 0x11u;
      while (ok != 0xFFu) {
#pragma unroll
        for (int i = 0; i < 8; ++i) {
          if (!(ok & (1u << i)))
            asm volatile("global_load_dwordx4 %0, %1, off sc0 sc1" : "=v"(pc[i])
                         : "v"((unsigned long long)(uintptr_t)(pb + i * 4)) : "memory");
        }
        asm volatile("s_waitcnt vmcnt(0)" ::: "memory");
#pragma unroll
        for (int i = 0; i < 8; ++i)
          if (!(ok & (1u << i)) && tag4(pc[i], exp_tag)) ok |= (1u << i);
        if (++guard > (1 << 18)) break;
      }
      // ---- strip -> Abuf (XOR-swizzled, b128 writes, ~4-way max conflict)
#pragma unroll
      for (int q2 = 0; q2 < 4; ++q2) {
        u32x4 a = pc[2 * q2], b = pc[2 * q2 + 1];
        short8 sv;
        sv[0] = (short)a.x; sv[1] = (short)a.y; sv[2] = (short)a.z; sv[3] = (short)a.w;
        sv[4] = (short)b.x; sv[5] = (short)b.y; sv[6] = (short)b.z; sv[7] = (short)b.w;
        *(short8*)&Abuf[(size_t)(cb * 64 + ((q2 * 16 + bb) ^ (cb & 7))) * 8] = sv;
      }
    }
    __syncthreads();  // B1: Abuf ready

    // ---- MFMA: 16x16 tile over K=1024, 4 independent chains
    f32x4 acc[4];
#pragma unroll
    for (int i = 0; i < 4; ++i) acc[i] = (f32x4){0.f, 0.f, 0.f, 0.f};
#pragma unroll
    for (int c = 0; c < 32; ++c) {
      short8 av = *(const short8*)&Abuf[(size_t)(c * 64 + (lane ^ (c & 7))) * 8];
      acc[c & 3] = __builtin_amdgcn_mfma_f32_16x16x32_bf16(av, Bfrag[c], acc[c & 3], 0, 0, 0);
    }
    __syncthreads();  // B2: Abuf consumed (next strip may overwrite)

    // ---- h = tanh(acc + xp), publish tagged dwords, head partial
    unsigned slotbase = (unsigned)(((s & 1) * 8 + g) * 16);
#pragma unroll
    for (int rr = 0; rr < 4; ++rr) {
      float h = ftanh(acc[0][rr] + acc[1][rr] + acc[2][rr] + acc[3][rr] + xpv[rr]);
      unsigned word = ((unsigned)s << 16) | (unsigned)f2bf(h);
      unsigned* pa = hbuf + (size_t)(slotbase + q * 4 + rr) * 1024 + gcol;
      asm volatile("global_store_dword %0, %1, off sc0 sc1"
                   :: "v"((unsigned long long)(uintptr_t)pa), "v"(word) : "memory");
      float pp = h * wfcv;
      pp += __shfl_xor(pp, 1, 64);
      pp += __shfl_xor(pp, 2, 64);
      pp += __shfl_xor(pp, 4, 64);
      pp += __shfl_xor(pp, 8, 64);
      if (r == 0)
        pscratch[(size_t)(s * 128 + b0 + q * 4 + rr) * 64 + p * 8 + w] = pp;
    }

    // ---- xp prefetch for s+1 (clamped; hides HBM latency under next poll)
    int sn = (s < 255) ? s + 1 : 255;
#pragma unroll
    for (int rr = 0; rr < 4; ++rr)
      xpv[rr] = bf2f(xp[((size_t)sn * 128 + b0 + q * 4 + rr) * 1024 + gcol]);
  }
}

// ---------------- head reduce: out[o] = sum_slot pscratch[o][slot] + bfc ----
__global__ __launch_bounds__(256) void head_reduce(const float* __restrict__ pscratch,
                                                   const float* __restrict__ bfc,
                                                   float* __restrict__ out) {
  int wid = blockIdx.x * 4 + (threadIdx.x >> 6);
  int l = threadIdx.x & 63;
  float v = pscratch[(size_t)wid * 64 + l];
#pragma unroll
  for (int off = 32; off; off >>= 1) v += __shfl_down(v, off, 64);
  if (l == 0) out[wid] = v + bfc[0];
}

// ---------------- launcher --------------------------------------------------
extern "C" void kernel_launch(void* const* d_in, const int* in_sizes, int n_in,
                              void* d_out, int out_size, void* d_ws, size_t ws_size,
                              hipStream_t stream) {
  (void)in_sizes; (void)n_in; (void)out_size; (void)ws_size;
  const float* x   = (const float*)d_in[0];
  const float* Wih = (const float*)d_in[1];
  const float* Whh = (const float*)d_in[2];
  const float* bih = (const float*)d_in[3];
  const float* bhh = (const float*)d_in[4];
  const float* Wfc = (const float*)d_in[5];
  const float* bfc = (const float*)d_in[6];
  float* out = (float*)d_out;

  char* ws = (char*)d_ws;
  // Layout: xp 64 MB @0 | xb 32 MB @64M (dead after gemm) | wb 1 MB @96M |
  // hbuf 1 MB @97M (tagged; poison-safe, tags checked by equality) |
  // pscratch 8 MB @98M (fully written each call). Total 106 MB.
  unsigned short* xp = (unsigned short*)(ws);
  unsigned short* xb = (unsigned short*)(ws + 67108864);
  unsigned short* wb = (unsigned short*)(ws + 100663296);
  unsigned* hbuf     = (unsigned*)(ws + 101711872);
  float* pscratch    = (float*)(ws + 102760448);

  cvt_kernel<<<8192, 256, 0, stream>>>(x, xb, 2097152);     // x fp32 -> bf16
  cvt_kernel<<<256, 256, 0, stream>>>(Wih, wb, 65536);      // W_ih fp32 -> bf16
  gemm_xp<<<2048, 256, 0, stream>>>(xb, wb, bih, bhh, xp);  // xp = x@W_ih^T + b
  scan_kernel<<<64, 512, 0, stream>>>(Whh, xp, Wfc, hbuf, pscratch);
  head_reduce<<<8192, 256, 0, stream>>>(pscratch, bfc, out);
}